// Round 22
// baseline (616.508 us; speedup 1.0000x reference)
//
#include <hip/hip_runtime.h>
#include <hip/hip_bf16.h>
#include <math.h>

#define B_TOK 8192
#define D_DIM 1024
#define H_DIM 4096
#define E_NUM 8
#define NPAIR (B_TOK * 2)
#define MT_WORST 93   // sum_e ceil(cnt_e/192) <= floor(16384/192)+8 = 93

typedef __bf16 bf16x8 __attribute__((ext_vector_type(8)));
typedef float f32x4 __attribute__((ext_vector_type(4)));
typedef unsigned short us4 __attribute__((ext_vector_type(4)));
typedef unsigned short us8 __attribute__((ext_vector_type(8)));

__device__ __forceinline__ unsigned short f2bf(float f) {
  union { float f; unsigned u; } v; v.f = f;
  unsigned r = v.u + 0x7FFFu + ((v.u >> 16) & 1u);
  return (unsigned short)(r >> 16);
}

__device__ __forceinline__ void gload16(const void* g, void* l) {
  __builtin_amdgcn_global_load_lds(
      (const __attribute__((address_space(1))) void*)g,
      (__attribute__((address_space(3))) void*)l, 16, 0, 0);
}

#define BARRIER()    asm volatile("s_barrier" ::: "memory")
#define VM5          asm volatile("s_waitcnt vmcnt(5)" ::: "memory")
#define VM0          asm volatile("s_waitcnt vmcnt(0)" ::: "memory")
#define LGKM0        asm volatile("s_waitcnt lgkmcnt(0)" ::: "memory")
#define RF(x) __builtin_amdgcn_readfirstlane(x)

// -- fused prep: router [0,2048) | x->bf16 [2048,10240) | w-transp [10240,26624)
__global__ void k_prep(const float* __restrict__ x, unsigned short* __restrict__ xb,
                       const float* __restrict__ w1, const float* __restrict__ w2,
                       unsigned short* __restrict__ w1t, unsigned short* __restrict__ w2t,
                       const float* __restrict__ wg, const float* __restrict__ bg,
                       int* __restrict__ tidx, float* __restrict__ tgate) {
  __shared__ unsigned short tl[64][68];
  int b = blockIdx.x;
  int tid = threadIdx.x;
  if (b < 2048) {
    int wid = tid >> 6, lane = tid & 63;
    int tok = b * 4 + wid;
    float acc[E_NUM];
#pragma unroll
    for (int e = 0; e < E_NUM; e++) acc[e] = 0.f;
    const float* xr = x + (size_t)tok * D_DIM;
#pragma unroll
    for (int it = 0; it < D_DIM / 256; it++) {
      int i = it * 256 + lane * 4;
      float4 xv = *(const float4*)(xr + i);
#pragma unroll
      for (int e = 0; e < E_NUM; e++) {
        float4 wv = *(const float4*)(wg + e * D_DIM + i);
        acc[e] += xv.x * wv.x + xv.y * wv.y + xv.z * wv.z + xv.w * wv.w;
      }
    }
#pragma unroll
    for (int e = 0; e < E_NUM; e++) {
#pragma unroll
      for (int off = 32; off; off >>= 1) acc[e] += __shfl_xor(acc[e], off);
    }
    if (lane == 0) {
      float v[E_NUM];
#pragma unroll
      for (int e = 0; e < E_NUM; e++) v[e] = acc[e] + bg[e];
      int i0 = 0; float v0 = v[0];
#pragma unroll
      for (int e = 1; e < E_NUM; e++) if (v[e] > v0) { v0 = v[e]; i0 = e; }
      int i1 = -1; float v1 = -1e30f;
#pragma unroll
      for (int e = 0; e < E_NUM; e++) if (e != i0 && v[e] > v1) { v1 = v[e]; i1 = e; }
      float g0 = 1.f / (1.f + expf(v1 - v0));
      float g1 = 1.f - g0;
      tidx[2 * tok] = i0; tidx[2 * tok + 1] = i1;
      tgate[2 * tok] = g0; tgate[2 * tok + 1] = g1;
    }
  } else if (b < 10240) {
    int i = ((b - 2048) * 256 + tid) * 4;
    float4 v = *(const float4*)(x + i);
    us4 o;
    o[0] = f2bf(v.x); o[1] = f2bf(v.y); o[2] = f2bf(v.z); o[3] = f2bf(v.w);
    *(us4*)(xb + i) = o;
  } else {
    int lb = b - 10240;            // 0..16383
    int which = lb >> 13;
    int rem = lb & 8191;
    int e = rem >> 10;
    int local = rem & 1023;
    int R = which ? H_DIM : D_DIM;
    int C = which ? D_DIM : H_DIM;
    int CT = C >> 6;
    int ct = local & (CT - 1);     // ct-fast => streaming reads
    int rt = local / CT;
    const float* ine = (which ? w2 : w1) + (size_t)e * D_DIM * H_DIM;
    unsigned short* oute = (which ? w2t : w1t) + (size_t)e * D_DIM * H_DIM;
    int r0 = rt * 64, c0 = ct * 64;
    int c4 = tid & 15, rg = tid >> 4;
    float4 v[4];
#pragma unroll
    for (int it = 0; it < 4; ++it)
      v[it] = *(const float4*)&ine[(size_t)(r0 + rg * 4 + it) * C + c0 + c4 * 4];
#pragma unroll
    for (int j = 0; j < 4; ++j) {
      us4 o;
      o[0] = f2bf(((const float*)&v[0])[j]);
      o[1] = f2bf(((const float*)&v[1])[j]);
      o[2] = f2bf(((const float*)&v[2])[j]);
      o[3] = f2bf(((const float*)&v[3])[j]);
      *(us4*)&tl[c4 * 4 + j][rg * 4] = o;
    }
    __syncthreads();
    int c = tid >> 2, g = tid & 3;
    us4 a0 = *(const us4*)&tl[c][g * 16 + 0];
    us4 a1 = *(const us4*)&tl[c][g * 16 + 4];
    us4 a2 = *(const us4*)&tl[c][g * 16 + 8];
    us4 a3 = *(const us4*)&tl[c][g * 16 + 12];
    us8 o0 = {a0[0], a0[1], a0[2], a0[3], a1[0], a1[1], a1[2], a1[3]};
    us8 o1 = {a2[0], a2[1], a2[2], a2[3], a3[0], a3[1], a3[2], a3[3]};
    size_t obase = (size_t)(c0 + c) * R + r0 + g * 16;
    *(us8*)&oute[obase] = o0;
    *(us8*)&oute[obase + 8] = o1;
  }
}

// ---- expert counting: LDS histogram -> 8 global atomics/block ----
__global__ void k_count(const int* __restrict__ tidx, int* __restrict__ cnt) {
  __shared__ int lcnt[E_NUM];
  int tid = threadIdx.x;
  if (tid < E_NUM) lcnt[tid] = 0;
  __syncthreads();
  int t = blockIdx.x * 256 + tid;
  atomicAdd(&lcnt[tidx[2 * t]], 1);
  atomicAdd(&lcnt[tidx[2 * t + 1]], 1);
  __syncthreads();
  if (tid < E_NUM) atomicAdd(&cnt[tid], lcnt[tid]);
}

// meta: cnt[8] @0 | eoff[9] @8 | cursor[8] @17 | toff1[9] @25 | toff2[9] @34
__global__ void k_prefix(int* __restrict__ meta) {
  if (threadIdx.x == 0) {
    int* cnt = meta;
    int* eoff = meta + 8;
    int* cursor = meta + 17;
    int* toff1 = meta + 25;
    int* toff2 = meta + 34;
    int a = 0, t1 = 0, t2 = 0;
    for (int e = 0; e < E_NUM; e++) {
      eoff[e] = a; cursor[e] = a; a += cnt[e];
      toff1[e] = t1; toff2[e] = t2;
      int mc = (cnt[e] + 191) / 192;   // ceil(cnt/192): 192-row M-tiles
      t1 += mc * (H_DIM / 128);            // GEMM1: KSPLIT=1
      t2 += mc * (D_DIM / 128) * 2;        // GEMM2: KSPLIT=2
    }
    eoff[E_NUM] = a; toff1[E_NUM] = t1; toff2[E_NUM] = t2;
  }
}

// ---- scatter: LDS-atomic local offsets + 8 global atomics/block for bases ----
__global__ void k_scatter(const int* __restrict__ tidx, const float* __restrict__ tgate,
                          int* __restrict__ cursor, int* __restrict__ ptok,
                          float* __restrict__ pgate) {
  __shared__ int lcnt[E_NUM];
  __shared__ int base[E_NUM];
  int tid = threadIdx.x;
  if (tid < E_NUM) lcnt[tid] = 0;
  __syncthreads();
  int t = blockIdx.x * 256 + tid;
  int e0 = tidx[2 * t], e1 = tidx[2 * t + 1];
  int l0 = atomicAdd(&lcnt[e0], 1);
  int l1 = atomicAdd(&lcnt[e1], 1);
  __syncthreads();
  if (tid < E_NUM) base[tid] = atomicAdd(&cursor[tid], lcnt[tid]);
  __syncthreads();
  int p0 = base[e0] + l0;
  int p1 = base[e1] + l1;
  ptok[p0] = t; pgate[p0] = tgate[2 * t];
  ptok[p1] = t; pgate[p1] = tgate[2 * t + 1];
}

// -- grouped GEMM, 192x128 tile, wave=96x64 (acc[6][4]=96 AGPR), BK=32 ------
// R21 structure + KSPLIT template (GEMM2=2 to fix makespan: 744 blocks on
// 512 slots was 1.45 rounds = 72% eff; 1488 -> 2.9 rounds = ~96%).
// Ring-3 single-barrier: step s reads buf s%3, stages step s+2 into the
// buffer freed at s-1 (WAR-safe at the barrier, R13 proof). VM5 steady
// (own 5 loads landed, next 5 in flight), VM0 only at final step.
// Tail: NKT==2 mod 3 -> 5-step tail (GEMM1, NKT=32); NKT==1 mod 3 ->
// 4-step tail (GEMM2 split, NKT=64). Bias applied only when kc==0.
template <int KDIM, int NDIM, int MODE, int KSPLIT>
__global__ __launch_bounds__(256, 2) void k_gemm(
    const unsigned short* __restrict__ A, const unsigned short* __restrict__ Bt,
    const float* __restrict__ bias, const int* __restrict__ meta,
    const int* __restrict__ ptok, const float* __restrict__ pgate,
    unsigned short* __restrict__ Hout, float* __restrict__ Out) {
  constexpr int NT = NDIM / 128;
  constexpr int KLEN = KDIM / KSPLIT;
  constexpr int NKT = KLEN / 32;
  static_assert((NKT % 3 == 2 || NKT % 3 == 1) && NKT >= 8, "tail variants");
  const int* eoff = meta + 8;
  const int* toff = (MODE == 1) ? (meta + 25) : (meta + 34);

  int tf[E_NUM + 1];
#pragma unroll
  for (int q = 0; q <= E_NUM; q++) tf[q] = RF(toff[q]);

  int nwg = gridDim.x;
  int bid = blockIdx.x;
  int i = (bid & 7) * (nwg >> 3) + (bid >> 3);  // XCD chunk swizzle (nwg%8==0)
  if (i >= tf[E_NUM]) return;
  int e = 0;
#pragma unroll
  for (int q = 1; q < E_NUM; q++) e += (i >= tf[q]);
  int r = i - tf[e];
  int mt = r / (NT * KSPLIT);
  int r2d = r - mt * (NT * KSPLIT);
  int nt = r2d / KSPLIT;
  int kc = r2d - nt * KSPLIT;
  int off = RF(eoff[e]);
  int cnt = RF(eoff[e + 1]) - off;
  int m0 = mt * 192;                            // m0 < cnt by construction
  int kbase = kc * KLEN;

  // [3 bufs][ A 192x32 (6144 sh) | B 128x32 (4096 sh) ] = 60 KB
  __shared__ unsigned short lds[3][6144 + 4096];

  int tid = threadIdx.x;
  int w = tid >> 6, lane = tid & 63;
  int wm = w >> 1, wn = w & 1;  // 2x2 wave grid; per-wave output 96x64

  int sseg = (lane & 3) ^ ((lane >> 3) & 3);
  const unsigned short* aSrc[3];
  const unsigned short* bSrc[2];
#pragma unroll
  for (int c = 0; c < 3; c++) {
    int q = w * 3 + c;
    int arow = m0 + q * 16 + (lane >> 2);
    int ar = (arow < cnt) ? arow : (cnt - 1);
    size_t grow;
    if (MODE == 1) grow = (size_t)ptok[off + ar];
    else grow = (size_t)(off + ar);
    aSrc[c] = A + grow * KDIM + kbase + sseg * 8;
  }
#pragma unroll
  for (int c = 0; c < 2; c++) {
    int q = w * 2 + c;
    int nrow = nt * 128 + q * 16 + (lane >> 2);
    bSrc[c] = Bt + (size_t)e * NDIM * KDIM + (size_t)nrow * KDIM + kbase + sseg * 8;
  }

  int segp = (lane >> 4) ^ ((lane >> 1) & 3);
  f32x4 acc[6][4] = {};

#define STAGE(buf, k0)                                              \
  {                                                                 \
    _Pragma("unroll")                                               \
    for (int c = 0; c < 3; c++)                                     \
      gload16(aSrc[c] + (k0), &lds[buf][(w * 3 + c) * 512]);        \
    _Pragma("unroll")                                               \
    for (int c = 0; c < 2; c++)                                     \
      gload16(bSrc[c] + (k0), &lds[buf][6144 + (w * 2 + c) * 512]); \
  }
#define NOSTG ((void)0)

#define STEP(buf, WAITC, STGC)                                              \
  {                                                                         \
    WAITC; BARRIER();                                                       \
    STGC;                                                                   \
    bf16x8 aF[6], bF[4];                                                    \
    _Pragma("unroll")                                                       \
    for (int m = 0; m < 6; m++) {                                           \
      int row = wm * 96 + m * 16 + (lane & 15);                             \
      aF[m] = *(const bf16x8*)&lds[buf][row * 32 + segp * 8];               \
    }                                                                       \
    _Pragma("unroll")                                                       \
    for (int n = 0; n < 4; n++) {                                           \
      int row = wn * 64 + n * 16 + (lane & 15);                             \
      bF[n] = *(const bf16x8*)&lds[buf][6144 + row * 32 + segp * 8];        \
    }                                                                       \
    LGKM0;                                                                  \
    __builtin_amdgcn_s_setprio(1);                                          \
    _Pragma("unroll")                                                       \
    for (int m = 0; m < 6; m++)                                             \
      _Pragma("unroll")                                                     \
      for (int n = 0; n < 4; n++)                                           \
        acc[m][n] =                                                         \
            __builtin_amdgcn_mfma_f32_16x16x32_bf16(aF[m], bF[n], acc[m][n], 0, 0, 0); \
    __builtin_amdgcn_s_setprio(0);                                          \
  }

  // prologue: 2 K-steps in flight (10 loads per thread)
  STAGE(0, 0);
  STAGE(1, 32);

  if constexpr (NKT % 3 == 2) {
#pragma unroll 1
    for (int kt = 0; kt < NKT - 5; kt += 3) {
      STEP(0, VM5, STAGE(2, (kt + 2) * 32));
      STEP(1, VM5, STAGE(0, (kt + 3) * 32));
      STEP(2, VM5, STAGE(1, (kt + 4) * 32));
    }
    STEP(0, VM5, STAGE(2, (NKT - 3) * 32));
    STEP(1, VM5, STAGE(0, (NKT - 2) * 32));
    STEP(2, VM5, STAGE(1, (NKT - 1) * 32));
    STEP(0, VM5, NOSTG);
    STEP(1, VM0, NOSTG);
  } else {  // NKT % 3 == 1: 4-step tail (steps NKT-4..NKT-1 = bufs 0,1,2,0)
#pragma unroll 1
    for (int kt = 0; kt < NKT - 4; kt += 3) {
      STEP(0, VM5, STAGE(2, (kt + 2) * 32));
      STEP(1, VM5, STAGE(0, (kt + 3) * 32));
      STEP(2, VM5, STAGE(1, (kt + 4) * 32));
    }
    STEP(0, VM5, STAGE(2, (NKT - 2) * 32));
    STEP(1, VM5, STAGE(0, (NKT - 1) * 32));
    STEP(2, VM5, NOSTG);
    STEP(0, VM0, NOSTG);
  }

#undef STAGE
#undef NOSTG
#undef STEP

  // epilogue: C/D map col=lane&15, row=(lane>>4)*4+r
#pragma unroll
  for (int m = 0; m < 6; m++) {
    int lrowb = wm * 96 + m * 16 + (lane >> 4) * 4;
#pragma unroll
    for (int r3 = 0; r3 < 4; r3++) {
      int arow = m0 + lrowb + r3;
      if (arow < cnt) {
        if constexpr (MODE == 1) {
          size_t rowbase = (size_t)(off + arow) * NDIM;
#pragma unroll
          for (int n = 0; n < 4; n++) {
            int col = nt * 128 + wn * 64 + n * 16 + (lane & 15);
            float v = acc[m][n][r3] + bias[e * NDIM + col];
            v = v > 0.f ? v : 0.f;
            Hout[rowbase + col] = f2bf(v);
          }
        } else {
          int tok = ptok[off + arow];
          float g = pgate[off + arow];
#pragma unroll
          for (int n = 0; n < 4; n++) {
            int col = nt * 128 + wn * 64 + n * 16 + (lane & 15);
            float bb = (kc == 0) ? bias[e * NDIM + col] : 0.f;
            float v = (acc[m][n][r3] + bb) * g;
            atomicAdd(Out + (size_t)tok * D_DIM + col, v);
          }
        }
      }
    }
  }
}

extern "C" void kernel_launch(void* const* d_in, const int* in_sizes, int n_in,
                              void* d_out, int out_size, void* d_ws, size_t ws_size,
                              hipStream_t stream) {
  const float* x  = (const float*)d_in[0];
  const float* wg = (const float*)d_in[1];
  const float* bg = (const float*)d_in[2];
  const float* w1 = (const float*)d_in[3];
  const float* b1 = (const float*)d_in[4];
  const float* w2 = (const float*)d_in[5];
  const float* b2 = (const float*)d_in[6];
  float* out = (float*)d_out;

  char* ws = (char*)d_ws;
  unsigned short* xb = (unsigned short*)ws;   ws += (size_t)B_TOK * D_DIM * 2;
  unsigned short* w1t = (unsigned short*)ws;  ws += (size_t)E_NUM * D_DIM * H_DIM * 2;
  unsigned short* w2t = (unsigned short*)ws;  ws += (size_t)E_NUM * D_DIM * H_DIM * 2;
  unsigned short* Hbuf = (unsigned short*)ws; ws += (size_t)NPAIR * H_DIM * 2;
  int* tidx = (int*)ws;    ws += (size_t)NPAIR * 4;
  float* tgate = (float*)ws; ws += (size_t)NPAIR * 4;
  int* ptok = (int*)ws;    ws += (size_t)NPAIR * 4;
  float* pgate = (float*)ws; ws += (size_t)NPAIR * 4;
  int* meta = (int*)ws;  // cnt[8] | eoff[9] | cursor[8] | toff1[9] | toff2[9]
  int* cnt = meta;
  int* cursor = meta + 17;

  hipMemsetAsync(meta, 0, 64 * sizeof(int), stream);
  hipMemsetAsync(out, 0, (size_t)out_size * sizeof(float), stream);

  k_prep<<<2048 + 8192 + 16384, 256, 0, stream>>>(
      x, xb, w1, w2, w1t, w2t, wg, bg, tidx, tgate);
  k_count<<<B_TOK / 256, 256, 0, stream>>>(tidx, cnt);
  k_prefix<<<1, 64, 0, stream>>>(meta);
  k_scatter<<<B_TOK / 256, 256, 0, stream>>>(tidx, tgate, cursor, ptok, pgate);
  // worst-case compact grids: G1 = 93*32 = 2976, G2 = 93*8*2 = 1488 (%8==0)
  k_gemm<D_DIM, H_DIM, 1, 1><<<MT_WORST * (H_DIM / 128), 256, 0, stream>>>(
      xb, w1t, b1, meta, ptok, pgate, Hbuf, nullptr);
  k_gemm<H_DIM, D_DIM, 2, 2><<<MT_WORST * (D_DIM / 128) * 2, 256, 0, stream>>>(
      Hbuf, w2t, b2, meta, ptok, pgate, nullptr, out);
}

// Round 23
// 563.552 us; speedup vs baseline: 1.0940x; 1.0940x over previous
//
#include <hip/hip_runtime.h>
#include <hip/hip_bf16.h>
#include <math.h>

#define B_TOK 8192
#define D_DIM 1024
#define H_DIM 4096
#define E_NUM 8
#define NPAIR (B_TOK * 2)
#define MT_WORST 93   // sum_e ceil(cnt_e/192) <= floor(16384/192)+8 = 93

typedef __bf16 bf16x8 __attribute__((ext_vector_type(8)));
typedef float f32x4 __attribute__((ext_vector_type(4)));
typedef unsigned short us4 __attribute__((ext_vector_type(4)));
typedef unsigned short us8 __attribute__((ext_vector_type(8)));

__device__ __forceinline__ unsigned short f2bf(float f) {
  union { float f; unsigned u; } v; v.f = f;
  unsigned r = v.u + 0x7FFFu + ((v.u >> 16) & 1u);
  return (unsigned short)(r >> 16);
}

__device__ __forceinline__ void gload16(const void* g, void* l) {
  __builtin_amdgcn_global_load_lds(
      (const __attribute__((address_space(1))) void*)g,
      (__attribute__((address_space(3))) void*)l, 16, 0, 0);
}

#define BARRIER()    asm volatile("s_barrier" ::: "memory")
#define VM5          asm volatile("s_waitcnt vmcnt(5)" ::: "memory")
#define VM0          asm volatile("s_waitcnt vmcnt(0)" ::: "memory")
#define LGKM0        asm volatile("s_waitcnt lgkmcnt(0)" ::: "memory")
#define RF(x) __builtin_amdgcn_readfirstlane(x)

// -- fused prep: router [0,2048) | x->bf16 [2048,10240) | w-transp [10240,26624)
// Router branch writes tidx/tgate ONLY (no hot global atomics — R20 win).
__global__ void k_prep(const float* __restrict__ x, unsigned short* __restrict__ xb,
                       const float* __restrict__ w1, const float* __restrict__ w2,
                       unsigned short* __restrict__ w1t, unsigned short* __restrict__ w2t,
                       const float* __restrict__ wg, const float* __restrict__ bg,
                       int* __restrict__ tidx, float* __restrict__ tgate) {
  __shared__ unsigned short tl[64][68];
  int b = blockIdx.x;
  int tid = threadIdx.x;
  if (b < 2048) {
    int wid = tid >> 6, lane = tid & 63;
    int tok = b * 4 + wid;
    float acc[E_NUM];
#pragma unroll
    for (int e = 0; e < E_NUM; e++) acc[e] = 0.f;
    const float* xr = x + (size_t)tok * D_DIM;
#pragma unroll
    for (int it = 0; it < D_DIM / 256; it++) {
      int i = it * 256 + lane * 4;
      float4 xv = *(const float4*)(xr + i);
#pragma unroll
      for (int e = 0; e < E_NUM; e++) {
        float4 wv = *(const float4*)(wg + e * D_DIM + i);
        acc[e] += xv.x * wv.x + xv.y * wv.y + xv.z * wv.z + xv.w * wv.w;
      }
    }
#pragma unroll
    for (int e = 0; e < E_NUM; e++) {
#pragma unroll
      for (int off = 32; off; off >>= 1) acc[e] += __shfl_xor(acc[e], off);
    }
    if (lane == 0) {
      float v[E_NUM];
#pragma unroll
      for (int e = 0; e < E_NUM; e++) v[e] = acc[e] + bg[e];
      int i0 = 0; float v0 = v[0];
#pragma unroll
      for (int e = 1; e < E_NUM; e++) if (v[e] > v0) { v0 = v[e]; i0 = e; }
      int i1 = -1; float v1 = -1e30f;
#pragma unroll
      for (int e = 0; e < E_NUM; e++) if (e != i0 && v[e] > v1) { v1 = v[e]; i1 = e; }
      float g0 = 1.f / (1.f + expf(v1 - v0));
      float g1 = 1.f - g0;
      tidx[2 * tok] = i0; tidx[2 * tok + 1] = i1;
      tgate[2 * tok] = g0; tgate[2 * tok + 1] = g1;
    }
  } else if (b < 10240) {
    int i = ((b - 2048) * 256 + tid) * 4;
    float4 v = *(const float4*)(x + i);
    us4 o;
    o[0] = f2bf(v.x); o[1] = f2bf(v.y); o[2] = f2bf(v.z); o[3] = f2bf(v.w);
    *(us4*)(xb + i) = o;
  } else {
    int lb = b - 10240;            // 0..16383
    int which = lb >> 13;
    int rem = lb & 8191;
    int e = rem >> 10;
    int local = rem & 1023;
    int R = which ? H_DIM : D_DIM;
    int C = which ? D_DIM : H_DIM;
    int CT = C >> 6;
    int ct = local & (CT - 1);     // ct-fast => streaming reads
    int rt = local / CT;
    const float* ine = (which ? w2 : w1) + (size_t)e * D_DIM * H_DIM;
    unsigned short* oute = (which ? w2t : w1t) + (size_t)e * D_DIM * H_DIM;
    int r0 = rt * 64, c0 = ct * 64;
    int c4 = tid & 15, rg = tid >> 4;
    float4 v[4];
#pragma unroll
    for (int it = 0; it < 4; ++it)
      v[it] = *(const float4*)&ine[(size_t)(r0 + rg * 4 + it) * C + c0 + c4 * 4];
#pragma unroll
    for (int j = 0; j < 4; ++j) {
      us4 o;
      o[0] = f2bf(((const float*)&v[0])[j]);
      o[1] = f2bf(((const float*)&v[1])[j]);
      o[2] = f2bf(((const float*)&v[2])[j]);
      o[3] = f2bf(((const float*)&v[3])[j]);
      *(us4*)&tl[c4 * 4 + j][rg * 4] = o;
    }
    __syncthreads();
    int c = tid >> 2, g = tid & 3;
    us4 a0 = *(const us4*)&tl[c][g * 16 + 0];
    us4 a1 = *(const us4*)&tl[c][g * 16 + 4];
    us4 a2 = *(const us4*)&tl[c][g * 16 + 8];
    us4 a3 = *(const us4*)&tl[c][g * 16 + 12];
    us8 o0 = {a0[0], a0[1], a0[2], a0[3], a1[0], a1[1], a1[2], a1[3]};
    us8 o1 = {a2[0], a2[1], a2[2], a2[3], a3[0], a3[1], a3[2], a3[3]};
    size_t obase = (size_t)(c0 + c) * R + r0 + g * 16;
    *(us8*)&oute[obase] = o0;
    *(us8*)&oute[obase + 8] = o1;
  }
}

// ---- expert counting: LDS histogram -> 8 global atomics/block ----
__global__ void k_count(const int* __restrict__ tidx, int* __restrict__ cnt) {
  __shared__ int lcnt[E_NUM];
  int tid = threadIdx.x;
  if (tid < E_NUM) lcnt[tid] = 0;
  __syncthreads();
  int t = blockIdx.x * 256 + tid;
  atomicAdd(&lcnt[tidx[2 * t]], 1);
  atomicAdd(&lcnt[tidx[2 * t + 1]], 1);
  __syncthreads();
  if (tid < E_NUM) atomicAdd(&cnt[tid], lcnt[tid]);
}

// meta: cnt[8] @0 | eoff[9] @8 | cursor[8] @17 | toff1[9] @25 | toff2[9] @34
__global__ void k_prefix(int* __restrict__ meta) {
  if (threadIdx.x == 0) {
    int* cnt = meta;
    int* eoff = meta + 8;
    int* cursor = meta + 17;
    int* toff1 = meta + 25;
    int* toff2 = meta + 34;
    int a = 0, t1 = 0, t2 = 0;
    for (int e = 0; e < E_NUM; e++) {
      eoff[e] = a; cursor[e] = a; a += cnt[e];
      toff1[e] = t1; toff2[e] = t2;
      int mc = (cnt[e] + 191) / 192;   // ceil(cnt/192): 192-row M-tiles
      t1 += mc * (H_DIM / 128);
      t2 += mc * (D_DIM / 128);
    }
    eoff[E_NUM] = a; toff1[E_NUM] = t1; toff2[E_NUM] = t2;
  }
}

// ---- scatter: LDS-atomic local offsets + 8 global atomics/block for bases ----
__global__ void k_scatter(const int* __restrict__ tidx, const float* __restrict__ tgate,
                          int* __restrict__ cursor, int* __restrict__ ptok,
                          float* __restrict__ pgate) {
  __shared__ int lcnt[E_NUM];
  __shared__ int base[E_NUM];
  int tid = threadIdx.x;
  if (tid < E_NUM) lcnt[tid] = 0;
  __syncthreads();
  int t = blockIdx.x * 256 + tid;
  int e0 = tidx[2 * t], e1 = tidx[2 * t + 1];
  int l0 = atomicAdd(&lcnt[e0], 1);
  int l1 = atomicAdd(&lcnt[e1], 1);
  __syncthreads();
  if (tid < E_NUM) base[tid] = atomicAdd(&cursor[tid], lcnt[tid]);
  __syncthreads();
  int p0 = base[e0] + l0;
  int p1 = base[e1] + l1;
  ptok[p0] = t; pgate[p0] = tgate[2 * t];
  ptok[p1] = t; pgate[p1] = tgate[2 * t + 1];
}

// -- grouped GEMM, 192x128 tile, wave=96x64 (acc[6][4]=96 AGPR), BK=32 ------
// R13 ring-3 single-barrier schedule, scaled: 10 ds_read_b128 feed 24 MFMA
// per wave-step. Per wave per step: 3 A-chunk + 2 B-chunk gload_lds (5
// loads) -> counted VM5 (own 5 landed, next 5 in flight). LDS 3x(A 192x32
// + B 128x32) = 60 KB, 2 blk/CU. Best measured config (R21: 564 us total).
// MODE 1: A = xb gathered via ptok, out = relu(A@B^T + b1) -> Hbuf (bf16)
// MODE 2: A = Hbuf rows direct,   out = (A@B^T + b2)*gate atomicAdd-> Out
template <int KDIM, int NDIM, int MODE>
__global__ __launch_bounds__(256, 2) void k_gemm(
    const unsigned short* __restrict__ A, const unsigned short* __restrict__ Bt,
    const float* __restrict__ bias, const int* __restrict__ meta,
    const int* __restrict__ ptok, const float* __restrict__ pgate,
    unsigned short* __restrict__ Hout, float* __restrict__ Out) {
  constexpr int NT = NDIM / 128;
  constexpr int NKT = KDIM / 32;
  static_assert(NKT % 3 == 2 && NKT >= 8, "tail pattern requires NKT==2 mod 3");
  const int* eoff = meta + 8;
  const int* toff = (MODE == 1) ? (meta + 25) : (meta + 34);

  int tf[E_NUM + 1];
#pragma unroll
  for (int q = 0; q <= E_NUM; q++) tf[q] = RF(toff[q]);

  int nwg = gridDim.x;
  int bid = blockIdx.x;
  int i = (bid & 7) * (nwg >> 3) + (bid >> 3);  // XCD chunk swizzle (nwg%8==0)
  if (i >= tf[E_NUM]) return;
  int e = 0;
#pragma unroll
  for (int q = 1; q < E_NUM; q++) e += (i >= tf[q]);
  int r = i - tf[e];
  int mt = r / NT;
  int nt = r - mt * NT;
  int off = RF(eoff[e]);
  int cnt = RF(eoff[e + 1]) - off;
  int m0 = mt * 192;                            // m0 < cnt by construction

  // [3 bufs][ A 192x32 (6144 sh) | B 128x32 (4096 sh) ] = 60 KB
  __shared__ unsigned short lds[3][6144 + 4096];

  int tid = threadIdx.x;
  int w = tid >> 6, lane = tid & 63;
  int wm = w >> 1, wn = w & 1;  // 2x2 wave grid; per-wave output 96x64

  int sseg = (lane & 3) ^ ((lane >> 3) & 3);
  const unsigned short* aSrc[3];
  const unsigned short* bSrc[2];
#pragma unroll
  for (int c = 0; c < 3; c++) {
    int q = w * 3 + c;
    int arow = m0 + q * 16 + (lane >> 2);
    int ar = (arow < cnt) ? arow : (cnt - 1);
    size_t grow;
    if (MODE == 1) grow = (size_t)ptok[off + ar];
    else grow = (size_t)(off + ar);
    aSrc[c] = A + grow * KDIM + sseg * 8;
  }
#pragma unroll
  for (int c = 0; c < 2; c++) {
    int q = w * 2 + c;
    int nrow = nt * 128 + q * 16 + (lane >> 2);
    bSrc[c] = Bt + (size_t)e * NDIM * KDIM + (size_t)nrow * KDIM + sseg * 8;
  }

  int segp = (lane >> 4) ^ ((lane >> 1) & 3);
  f32x4 acc[6][4] = {};

#define STAGE(buf, k0)                                              \
  {                                                                 \
    _Pragma("unroll")                                               \
    for (int c = 0; c < 3; c++)                                     \
      gload16(aSrc[c] + (k0), &lds[buf][(w * 3 + c) * 512]);        \
    _Pragma("unroll")                                               \
    for (int c = 0; c < 2; c++)                                     \
      gload16(bSrc[c] + (k0), &lds[buf][6144 + (w * 2 + c) * 512]); \
  }
#define NOSTG ((void)0)

#define STEP(buf, WAITC, STGC)                                              \
  {                                                                         \
    WAITC; BARRIER();                                                       \
    STGC;                                                                   \
    bf16x8 aF[6], bF[4];                                                    \
    _Pragma("unroll")                                                       \
    for (int m = 0; m < 6; m++) {                                           \
      int row = wm * 96 + m * 16 + (lane & 15);                             \
      aF[m] = *(const bf16x8*)&lds[buf][row * 32 + segp * 8];               \
    }                                                                       \
    _Pragma("unroll")                                                       \
    for (int n = 0; n < 4; n++) {                                           \
      int row = wn * 64 + n * 16 + (lane & 15);                             \
      bF[n] = *(const bf16x8*)&lds[buf][6144 + row * 32 + segp * 8];        \
    }                                                                       \
    LGKM0;                                                                  \
    __builtin_amdgcn_s_setprio(1);                                          \
    _Pragma("unroll")                                                       \
    for (int m = 0; m < 6; m++)                                             \
      _Pragma("unroll")                                                     \
      for (int n = 0; n < 4; n++)                                           \
        acc[m][n] =                                                         \
            __builtin_amdgcn_mfma_f32_16x16x32_bf16(aF[m], bF[n], acc[m][n], 0, 0, 0); \
    __builtin_amdgcn_s_setprio(0);                                          \
  }

  // prologue: 2 K-steps in flight (10 loads per thread)
  STAGE(0, 0);
  STAGE(1, 32);

#pragma unroll 1
  for (int kt = 0; kt < NKT - 5; kt += 3) {
    STEP(0, VM5, STAGE(2, (kt + 2) * 32));
    STEP(1, VM5, STAGE(0, (kt + 3) * 32));
    STEP(2, VM5, STAGE(1, (kt + 4) * 32));
  }
  STEP(0, VM5, STAGE(2, (NKT - 3) * 32));
  STEP(1, VM5, STAGE(0, (NKT - 2) * 32));
  STEP(2, VM5, STAGE(1, (NKT - 1) * 32));
  STEP(0, VM5, NOSTG);
  STEP(1, VM0, NOSTG);

#undef STAGE
#undef NOSTG
#undef STEP

  // epilogue: C/D map col=lane&15, row=(lane>>4)*4+r
#pragma unroll
  for (int m = 0; m < 6; m++) {
    int lrowb = wm * 96 + m * 16 + (lane >> 4) * 4;
#pragma unroll
    for (int r2 = 0; r2 < 4; r2++) {
      int arow = m0 + lrowb + r2;
      if (arow < cnt) {
        if constexpr (MODE == 1) {
          size_t rowbase = (size_t)(off + arow) * NDIM;
#pragma unroll
          for (int n = 0; n < 4; n++) {
            int col = nt * 128 + wn * 64 + n * 16 + (lane & 15);
            float v = acc[m][n][r2] + bias[e * NDIM + col];
            v = v > 0.f ? v : 0.f;
            Hout[rowbase + col] = f2bf(v);
          }
        } else {
          int tok = ptok[off + arow];
          float g = pgate[off + arow];
#pragma unroll
          for (int n = 0; n < 4; n++) {
            int col = nt * 128 + wn * 64 + n * 16 + (lane & 15);
            float v = (acc[m][n][r2] + bias[e * NDIM + col]) * g;
            atomicAdd(Out + (size_t)tok * D_DIM + col, v);
          }
        }
      }
    }
  }
}

extern "C" void kernel_launch(void* const* d_in, const int* in_sizes, int n_in,
                              void* d_out, int out_size, void* d_ws, size_t ws_size,
                              hipStream_t stream) {
  const float* x  = (const float*)d_in[0];
  const float* wg = (const float*)d_in[1];
  const float* bg = (const float*)d_in[2];
  const float* w1 = (const float*)d_in[3];
  const float* b1 = (const float*)d_in[4];
  const float* w2 = (const float*)d_in[5];
  const float* b2 = (const float*)d_in[6];
  float* out = (float*)d_out;

  char* ws = (char*)d_ws;
  unsigned short* xb = (unsigned short*)ws;   ws += (size_t)B_TOK * D_DIM * 2;
  unsigned short* w1t = (unsigned short*)ws;  ws += (size_t)E_NUM * D_DIM * H_DIM * 2;
  unsigned short* w2t = (unsigned short*)ws;  ws += (size_t)E_NUM * D_DIM * H_DIM * 2;
  unsigned short* Hbuf = (unsigned short*)ws; ws += (size_t)NPAIR * H_DIM * 2;
  int* tidx = (int*)ws;    ws += (size_t)NPAIR * 4;
  float* tgate = (float*)ws; ws += (size_t)NPAIR * 4;
  int* ptok = (int*)ws;    ws += (size_t)NPAIR * 4;
  float* pgate = (float*)ws; ws += (size_t)NPAIR * 4;
  int* meta = (int*)ws;  // cnt[8] | eoff[9] | cursor[8] | toff1[9] | toff2[9]
  int* cnt = meta;
  int* cursor = meta + 17;

  hipMemsetAsync(meta, 0, 64 * sizeof(int), stream);
  hipMemsetAsync(out, 0, (size_t)out_size * sizeof(float), stream);

  k_prep<<<2048 + 8192 + 16384, 256, 0, stream>>>(
      x, xb, w1, w2, w1t, w2t, wg, bg, tidx, tgate);
  k_count<<<B_TOK / 256, 256, 0, stream>>>(tidx, cnt);
  k_prefix<<<1, 64, 0, stream>>>(meta);
  k_scatter<<<B_TOK / 256, 256, 0, stream>>>(tidx, tgate, cursor, ptok, pgate);
  // worst-case compact grids: MT_WORST=93 -> G1 = 93*32 = 2976 (%8==0),
  // G2 = 93*8 = 744 (%8==0)
  k_gemm<D_DIM, H_DIM, 1><<<MT_WORST * (H_DIM / 128), 256, 0, stream>>>(
      xb, w1t, b1, meta, ptok, pgate, Hbuf, nullptr);
  k_gemm<H_DIM, D_DIM, 2><<<MT_WORST * (D_DIM / 128), 256, 0, stream>>>(
      Hbuf, w2t, b2, meta, ptok, pgate, nullptr, out);
}